// Round 19
// baseline (22.027 us; speedup 1.0000x reference)
//
#include <hip/hip_runtime.h>
#include <math.h>

#define BB 4
#define NN 512
#define PP 2048
#define EE 32768
#define FH 128
#define DRBF 32
#define CUT 4.0f
#define PI_F 3.14159265358979323846f
#define NE 4
#define CHUNK 256         // raw edges per fused block (R12/R18-proven)
#define AT2 8             // atoms per atom_kernel block

// ws layout: O at ws+256: [2048 atoms][512] floats = 4.2 MB
//   O[a][  0..127]=M0  [128..255]=M1  [256..383]=M2 = V[a]@W1_q (rows 32..159)
//   O[a][384..511]=C  = n_e@W1_n (rows 160..287) + S@W1_s (rows 288..415) + b1

// Node 1: per-atom precompute + zero `out` (blocks 0-7). 4 fams x 256 groups;
// fam3 computes the combined C column (2x inner work). k-split register tile
// (R18-proven): thread = (kh in 8) x (fg in 32); 32 LDS b128/thread.
__global__ __launch_bounds__(256) void atom_kernel(
    const float* __restrict__ S, const float* __restrict__ V,
    const float* __restrict__ W1, const float* __restrict__ b1,
    float* __restrict__ O, float* __restrict__ out) {
  __shared__ float inS[AT2][128];       // 4 KB (V-comp, or n_e for fam3)
  __shared__ float in2S[AT2][128];      // 4 KB (fam3 only: S)
  __shared__ float red[8][AT2][128];    // 32 KB [kh][atom][feat]
  const int t = threadIdx.x;
  if (blockIdx.x < 8)
    ((float4*)out)[blockIdx.x * 256 + t] = make_float4(0.f, 0.f, 0.f, 0.f);

  const int fam = blockIdx.x & 3;
  const int a0  = (blockIdx.x >> 2) * AT2;

  // stage inputs (256 float4 per buffer, 1/thread)
  {
    int a  = t >> 5;          // 0..7
    int k4 = t & 31;          // float4 index 0..31
    if (fam < 3) {
      *(float4*)&inS[a][k4 * 4] =
        *(const float4*)&V[(size_t)(a0 + a) * 384 + fam * 128 + k4 * 4];
    } else {
      float4 x = *(const float4*)&V[(size_t)(a0 + a) * 384 +   0 + k4 * 4];
      float4 y = *(const float4*)&V[(size_t)(a0 + a) * 384 + 128 + k4 * 4];
      float4 z = *(const float4*)&V[(size_t)(a0 + a) * 384 + 256 + k4 * 4];
      float4 v;
      v.x = sqrtf(x.x*x.x + y.x*y.x + z.x*z.x);
      v.y = sqrtf(x.y*x.y + y.y*y.y + z.y*z.y);
      v.z = sqrtf(x.z*x.z + y.z*y.z + z.z*z.z);
      v.w = sqrtf(x.w*x.w + y.w*y.w + z.w*z.w);
      *(float4*)&inS[a][k4 * 4] = v;
      *(float4*)&in2S[a][k4 * 4] =
        *(const float4*)&S[(size_t)(a0 + a) * 128 + k4 * 4];
    }
  }
  __syncthreads();

  const int kh = t >> 5;     // k-slice: [kh*16, kh*16+16)
  const int fg = t & 31;     // feature quad
  const int k0 = kh * 16;

  float4 acc[AT2];
  #pragma unroll
  for (int a = 0; a < AT2; ++a) acc[a] = make_float4(0.f, 0.f, 0.f, 0.f);

  #define GEMM16(WROW, SRC)                                                          \
    { const float* Wb = W1 + (size_t)(WROW) * FH + fg * 4;                           \
      _Pragma("unroll 2")                                                            \
      for (int k4 = 0; k4 < 4; ++k4) {                                               \
        const int k = k0 + k4 * 4;                                                   \
        float4 w0 = *(const float4*)&Wb[(size_t)(k + 0) * FH];                       \
        float4 w1 = *(const float4*)&Wb[(size_t)(k + 1) * FH];                       \
        float4 w2 = *(const float4*)&Wb[(size_t)(k + 2) * FH];                       \
        float4 w3 = *(const float4*)&Wb[(size_t)(k + 3) * FH];                       \
        _Pragma("unroll")                                                            \
        for (int a = 0; a < AT2; ++a) {                                              \
          float4 hv = *(const float4*)&SRC[a][k];                                    \
          acc[a].x = fmaf(hv.x, w0.x, acc[a].x); acc[a].y = fmaf(hv.x, w0.y, acc[a].y); \
          acc[a].z = fmaf(hv.x, w0.z, acc[a].z); acc[a].w = fmaf(hv.x, w0.w, acc[a].w); \
          acc[a].x = fmaf(hv.y, w1.x, acc[a].x); acc[a].y = fmaf(hv.y, w1.y, acc[a].y); \
          acc[a].z = fmaf(hv.y, w1.z, acc[a].z); acc[a].w = fmaf(hv.y, w1.w, acc[a].w); \
          acc[a].x = fmaf(hv.z, w2.x, acc[a].x); acc[a].y = fmaf(hv.z, w2.y, acc[a].y); \
          acc[a].z = fmaf(hv.z, w2.z, acc[a].z); acc[a].w = fmaf(hv.z, w2.w, acc[a].w); \
          acc[a].x = fmaf(hv.w, w3.x, acc[a].x); acc[a].y = fmaf(hv.w, w3.y, acc[a].y); \
          acc[a].z = fmaf(hv.w, w3.z, acc[a].z); acc[a].w = fmaf(hv.w, w3.w, acc[a].w); \
        }                                                                            \
      } }

  if (fam == 0)      { GEMM16(32,  inS) }
  else if (fam == 1) { GEMM16(32,  inS) }   // same rows, different V-comp staged
  else if (fam == 2) { GEMM16(32,  inS) }
  else               { GEMM16(160, inS)     // n_e @ W1_n
                       GEMM16(288, in2S) }  // + S @ W1_s
  #undef GEMM16

  // kh-partial reduction through LDS
  #pragma unroll
  for (int a = 0; a < AT2; ++a)
    *(float4*)&red[kh][a][fg * 4] = acc[a];
  __syncthreads();
  {
    const int a  = t >> 5;
    const int fq = t & 31;
    float4 s = make_float4(0.f, 0.f, 0.f, 0.f);
    #pragma unroll
    for (int k2 = 0; k2 < 8; ++k2) {
      float4 v = *(const float4*)&red[k2][a][fq * 4];
      s.x += v.x; s.y += v.y; s.z += v.z; s.w += v.w;
    }
    if (fam == 3) {   // fold b1 into C
      float4 bv = *(const float4*)&b1[fq * 4];
      s.x += bv.x; s.y += bv.y; s.z += bv.z; s.w += bv.w;
    }
    *(float4*)&O[(size_t)(a0 + a) * 512 + fam * 128 + fq * 4] = s;
  }
}

// Node 2: fused filter + per-edge MLP (R12/R18 structure) with loop-invariant
// weight columns hoisted to registers and float4 ep reads.
__global__ __launch_bounds__(256) void fused_kernel(
    const int* __restrict__ pe, const float* __restrict__ pdisp,
    const float* __restrict__ cell, const float* __restrict__ atom_xyz,
    const float* __restrict__ probe_xyz,
    const float* __restrict__ O,
    const float* __restrict__ W1, const float* __restrict__ b1,
    const float* __restrict__ W2, const float* __restrict__ b2,
    const float* __restrict__ W3, const float* __restrict__ b3,
    float* __restrict__ out) {
  __shared__ float sdx[CHUNK], sdy[CHUNK], sdz[CHUNK];
  __shared__ unsigned sap[CHUNK];
  __shared__ int mcnt;
  __shared__ float epS[NE][DRBF];
  __shared__ float h2S[NE][FH];
  __shared__ float part2[4][NE][64];
  __shared__ float rS[NE][3];
  __shared__ unsigned aS[NE];
  __shared__ float cwS[NE];
  __shared__ unsigned pS[NE];

  const int t    = threadIdx.x;
  const int lane = t & 63;
  const int wave = t >> 6;
  if (t == 0) mcnt = 0;
  __syncthreads();

  // ---- Phase F: filter this block's 256 edges (1/thread) ----
  const int e = blockIdx.x * CHUNK + t;
  const int b = blockIdx.x >> 7;
  const float* cb = cell + b * 9;
  {
    int2 ap = ((const int2*)pe)[e];
    float pd0 = pdisp[e*3], pd1 = pdisp[e*3+1], pd2 = pdisp[e*3+2];
    float d0 = pd0*cb[0] + pd1*cb[3] + pd2*cb[6];
    float d1 = pd0*cb[1] + pd1*cb[4] + pd2*cb[7];
    float d2 = pd0*cb[2] + pd1*cb[5] + pd2*cb[8];
    int ag = b*NN + ap.x;
    int pg = b*PP + ap.y;
    float dx = probe_xyz[pg*3]   - (atom_xyz[ag*3]   + d0);
    float dy = probe_xyz[pg*3+1] - (atom_xyz[ag*3+1] + d1);
    float dz = probe_xyz[pg*3+2] - (atom_xyz[ag*3+2] + d2);
    float dist2 = dx*dx + dy*dy + dz*dz;
    if (dist2 < CUT*CUT) {
      int s = atomicAdd(&mcnt, 1);   // LDS atomic
      sdx[s] = dx; sdy[s] = dy; sdz[s] = dz;
      sap[s] = ((unsigned)ag << 16) | (unsigned)pg;
    }
  }
  __syncthreads();
  const int m = mcnt;
  if (m == 0) return;

  const int f1 = t & 127;     // L1 feature
  const int eh = t >> 7;      // L1 edge-half
  const float b2v = b2[lane];
  const float w3v = W3[lane];
  const float b3v = b3[0];

  // hoist loop-invariant weight columns into registers (static idx, no spill)
  float w1r[DRBF];            // W1 RBF rows, column f1
  #pragma unroll
  for (int k = 0; k < DRBF; ++k) w1r[k] = W1[k * FH + f1];
  float w2r[32];              // W2 k-quarter rows, column lane
  #pragma unroll
  for (int k = 0; k < 32; ++k) w2r[k] = W2[(wave * 32 + k) * 64 + lane];

  for (int s0 = 0; s0 < m; s0 += NE) {
    {
      const int s = s0 + wave;
      float dx, dy, dz; unsigned ap_;
      if (s < m) { dx = sdx[s]; dy = sdy[s]; dz = sdz[s]; ap_ = sap[s]; }
      else       { dx = 1.f; dy = 0.f; dz = 0.f; ap_ = 0xFFFFFFFFu; }
      float d = sqrtf(dx*dx + dy*dy + dz*dz);
      float inv = 1.0f / (d + 1e-8f);
      if (lane < DRBF) epS[wave][lane] = sinf(d * (float)(lane+1) * (PI_F/CUT)) / d;
      if (lane == 0) {
        rS[wave][0] = dx*inv; rS[wave][1] = dy*inv; rS[wave][2] = dz*inv;
        aS[wave] = (ap_ == 0xFFFFFFFFu) ? 0u : (ap_ >> 16);
        cwS[wave] = 0.5f * (cosf((PI_F/CUT) * d) + 1.0f);
        pS[wave]  = (ap_ == 0xFFFFFFFFu) ? 0xFFFFFFFFu : (ap_ & 0xFFFFu);
      }
    }
    __syncthreads();

    // L1: thread (f1, eh) -> z for edges eh*2, eh*2+1 (b1 folded into O's C col)
    {
      const int e0 = eh*2, e1 = eh*2 + 1;
      const float* Oa  = O + (size_t)aS[e0] * 512 + f1;
      const float* Obp = O + (size_t)aS[e1] * 512 + f1;
      float o00 = Oa[0],  o01 = Oa[128],  o02 = Oa[256],  oc0 = Oa[384];
      float o10 = Obp[0], o11 = Obp[128], o12 = Obp[256], oc1 = Obp[384];
      float z0 = oc0 + rS[e0][0]*o00 + rS[e0][1]*o01 + rS[e0][2]*o02;
      float z1 = oc1 + rS[e1][0]*o10 + rS[e1][1]*o11 + rS[e1][2]*o12;
      #pragma unroll
      for (int k4 = 0; k4 < DRBF/4; ++k4) {
        float4 ea = *(const float4*)&epS[e0][k4*4];
        float4 eb = *(const float4*)&epS[e1][k4*4];
        z0 = fmaf(ea.x, w1r[k4*4+0], z0); z1 = fmaf(eb.x, w1r[k4*4+0], z1);
        z0 = fmaf(ea.y, w1r[k4*4+1], z0); z1 = fmaf(eb.y, w1r[k4*4+1], z1);
        z0 = fmaf(ea.z, w1r[k4*4+2], z0); z1 = fmaf(eb.z, w1r[k4*4+2], z1);
        z0 = fmaf(ea.w, w1r[k4*4+3], z0); z1 = fmaf(eb.w, w1r[k4*4+3], z1);
      }
      h2S[e0][f1] = z0 / (1.0f + __expf(-z0));
      h2S[e1][f1] = z1 / (1.0f + __expf(-z1));
    }
    __syncthreads();

    // L2 (k-split): wave = k-quarter, lane = out-feature; weights in regs
    {
      float a0 = 0.f, a1 = 0.f, a2 = 0.f, a3 = 0.f;
      const float* h0p = &h2S[0][wave * 32];
      const float* h1p = &h2S[1][wave * 32];
      const float* h2p = &h2S[2][wave * 32];
      const float* h3p = &h2S[3][wave * 32];
      #pragma unroll
      for (int k4 = 0; k4 < 8; ++k4) {
        float4 h0 = *(const float4*)&h0p[k4*4];
        float4 h1 = *(const float4*)&h1p[k4*4];
        float4 h2 = *(const float4*)&h2p[k4*4];
        float4 h3 = *(const float4*)&h3p[k4*4];
        a0 = fmaf(h0.x, w2r[k4*4+0], a0); a1 = fmaf(h1.x, w2r[k4*4+0], a1);
        a2 = fmaf(h2.x, w2r[k4*4+0], a2); a3 = fmaf(h3.x, w2r[k4*4+0], a3);
        a0 = fmaf(h0.y, w2r[k4*4+1], a0); a1 = fmaf(h1.y, w2r[k4*4+1], a1);
        a2 = fmaf(h2.y, w2r[k4*4+1], a2); a3 = fmaf(h3.y, w2r[k4*4+1], a3);
        a0 = fmaf(h0.z, w2r[k4*4+2], a0); a1 = fmaf(h1.z, w2r[k4*4+2], a1);
        a2 = fmaf(h2.z, w2r[k4*4+2], a2); a3 = fmaf(h3.z, w2r[k4*4+2], a3);
        a0 = fmaf(h0.w, w2r[k4*4+3], a0); a1 = fmaf(h1.w, w2r[k4*4+3], a1);
        a2 = fmaf(h2.w, w2r[k4*4+3], a2); a3 = fmaf(h3.w, w2r[k4*4+3], a3);
      }
      part2[wave][0][lane] = a0;
      part2[wave][1][lane] = a1;
      part2[wave][2][lane] = a2;
      part2[wave][3][lane] = a3;
    }
    __syncthreads();

    // finish: wave = edge, lane = out-feature; silu + W3-dot + scatter
    {
      float z = part2[0][wave][lane] + part2[1][wave][lane]
              + part2[2][wave][lane] + part2[3][wave][lane] + b2v;
      float h2 = z / (1.0f + __expf(-z));
      float rs = h2 * w3v;
      #pragma unroll
      for (int off = 32; off; off >>= 1) rs += __shfl_xor(rs, off, 64);
      if (lane == 0) {
        unsigned p = pS[wave];
        if (p != 0xFFFFFFFFu) atomicAdd(&out[p], (rs + b3v) * cwS[wave]);
      }
    }
    __syncthreads();
  }
}

extern "C" void kernel_launch(void* const* d_in, const int* in_sizes, int n_in,
                              void* d_out, int out_size, void* d_ws, size_t ws_size,
                              hipStream_t stream) {
  const float* S         = (const float*)d_in[0];
  const float* V         = (const float*)d_in[1];
  const float* atom_xyz  = (const float*)d_in[2];
  const float* probe_xyz = (const float*)d_in[3];
  const float* cell      = (const float*)d_in[4];
  const float* pdisp     = (const float*)d_in[5];
  const float* W1        = (const float*)d_in[6];
  const float* b1        = (const float*)d_in[7];
  const float* W2        = (const float*)d_in[8];
  const float* b2        = (const float*)d_in[9];
  const float* W3        = (const float*)d_in[10];
  const float* b3        = (const float*)d_in[11];
  const int*   pe        = (const int*)d_in[12];
  float* out = (float*)d_out;

  float* O = (float*)((char*)d_ws + 256);   // 2048 x 512 floats

  atom_kernel<<<(BB*NN/AT2)*4, 256, 0, stream>>>(S, V, W1, b1, O, out);
  fused_kernel<<<BB*EE/CHUNK, 256, 0, stream>>>(pe, pdisp, cell, atom_xyz, probe_xyz,
                                                O, W1, b1, W2, b2, W3, b3, out);
}

// Round 20
// 19.519 us; speedup vs baseline: 1.1285x; 1.1285x over previous
//
#include <hip/hip_runtime.h>
#include <math.h>

#define BB 4
#define NN 512
#define PP 2048
#define EE 32768
#define FH 128
#define DRBF 32
#define CUT 4.0f
#define PI_F 3.14159265358979323846f
#define NE 4
#define CHUNK 256         // raw edges per fused block (R12/R18-proven)
#define AT2 8             // atoms per atom_kernel block

// ws layout: O at ws+256: [2048 atoms][640] floats = 5.24 MB
//   O[a][  0..127]=M0  [128..255]=M1  [256..383]=M2 = V[a]@W1_q (rows 32..159)
//   O[a][384..511]=Cn = n_e@W1_n (rows 160..287)
//   O[a][512..639]=Cs = S@W1_s  (rows 288..415)

// Node 1: per-atom precompute + zero `out` (blocks 0-7). R18-proven k-split
// register tile: thread = (kh in 8 k-slices) x (fg in 32 feat-quads);
// 32 LDS b128/thread (4x fewer than R12's 128); W1 read once per block.
__global__ __launch_bounds__(256) void atom_kernel(
    const float* __restrict__ S, const float* __restrict__ V,
    const float* __restrict__ W1, float* __restrict__ O,
    float* __restrict__ out) {
  __shared__ float inS[AT2][128];       // 4 KB
  __shared__ float red[8][AT2][128];    // 32 KB [kh][atom][feat]
  const int t = threadIdx.x;
  if (blockIdx.x < 8)
    ((float4*)out)[blockIdx.x * 256 + t] = make_float4(0.f, 0.f, 0.f, 0.f);

  const int fam = blockIdx.x % 5;
  const int a0  = (blockIdx.x / 5) * AT2;

  // stage the needed 128-vector per atom (256 float4, 1/thread)
  {
    int a  = t >> 5;          // 0..7
    int k4 = t & 31;          // float4 index 0..31
    float4 v;
    if (fam < 3) {
      v = *(const float4*)&V[(size_t)(a0 + a) * 384 + fam * 128 + k4 * 4];
    } else if (fam == 4) {
      v = *(const float4*)&S[(size_t)(a0 + a) * 128 + k4 * 4];
    } else { // fam == 3: n_e from V
      float4 x = *(const float4*)&V[(size_t)(a0 + a) * 384 +   0 + k4 * 4];
      float4 y = *(const float4*)&V[(size_t)(a0 + a) * 384 + 128 + k4 * 4];
      float4 z = *(const float4*)&V[(size_t)(a0 + a) * 384 + 256 + k4 * 4];
      v.x = sqrtf(x.x*x.x + y.x*y.x + z.x*z.x);
      v.y = sqrtf(x.y*x.y + y.y*y.y + z.y*z.y);
      v.z = sqrtf(x.z*x.z + y.z*y.z + z.z*z.z);
      v.w = sqrtf(x.w*x.w + y.w*y.w + z.w*z.w);
    }
    *(float4*)&inS[a][k4 * 4] = v;
  }
  __syncthreads();

  const int kh = t >> 5;     // k-slice: k in [kh*16, kh*16+16)
  const int fg = t & 31;     // feature quad: feats fg*4 .. fg*4+3
  const int k0 = kh * 16;
  const int wrow = (fam < 3) ? 32 : ((fam == 3) ? 160 : 288);
  const float* Wb = W1 + (size_t)wrow * FH + fg * 4;

  float4 acc[AT2];
  #pragma unroll
  for (int a = 0; a < AT2; ++a) acc[a] = make_float4(0.f, 0.f, 0.f, 0.f);

  #pragma unroll 2
  for (int k4 = 0; k4 < 4; ++k4) {
    const int k = k0 + k4 * 4;
    float4 w0 = *(const float4*)&Wb[(size_t)(k + 0) * FH];
    float4 w1 = *(const float4*)&Wb[(size_t)(k + 1) * FH];
    float4 w2 = *(const float4*)&Wb[(size_t)(k + 2) * FH];
    float4 w3 = *(const float4*)&Wb[(size_t)(k + 3) * FH];
    #pragma unroll
    for (int a = 0; a < AT2; ++a) {
      float4 hv = *(const float4*)&inS[a][k];
      acc[a].x = fmaf(hv.x, w0.x, acc[a].x); acc[a].y = fmaf(hv.x, w0.y, acc[a].y);
      acc[a].z = fmaf(hv.x, w0.z, acc[a].z); acc[a].w = fmaf(hv.x, w0.w, acc[a].w);
      acc[a].x = fmaf(hv.y, w1.x, acc[a].x); acc[a].y = fmaf(hv.y, w1.y, acc[a].y);
      acc[a].z = fmaf(hv.y, w1.z, acc[a].z); acc[a].w = fmaf(hv.y, w1.w, acc[a].w);
      acc[a].x = fmaf(hv.z, w2.x, acc[a].x); acc[a].y = fmaf(hv.z, w2.y, acc[a].y);
      acc[a].z = fmaf(hv.z, w2.z, acc[a].z); acc[a].w = fmaf(hv.z, w2.w, acc[a].w);
      acc[a].x = fmaf(hv.w, w3.x, acc[a].x); acc[a].y = fmaf(hv.w, w3.y, acc[a].y);
      acc[a].z = fmaf(hv.w, w3.z, acc[a].z); acc[a].w = fmaf(hv.w, w3.w, acc[a].w);
    }
  }

  // kh-partial reduction through LDS (contiguous float4, conflict-free)
  #pragma unroll
  for (int a = 0; a < AT2; ++a)
    *(float4*)&red[kh][a][fg * 4] = acc[a];
  __syncthreads();
  {
    const int a  = t >> 5;
    const int fq = t & 31;
    float4 s = make_float4(0.f, 0.f, 0.f, 0.f);
    #pragma unroll
    for (int k2 = 0; k2 < 8; ++k2) {
      float4 v = *(const float4*)&red[k2][a][fq * 4];
      s.x += v.x; s.y += v.y; s.z += v.z; s.w += v.w;
    }
    *(float4*)&O[(size_t)(a0 + a) * 640 + fam * 128 + fq * 4] = s;
  }
}

// Node 2: fused filter + per-edge MLP (R18 champion structure; single change:
// L1 epS reads vectorized to float4 broadcasts).
__global__ __launch_bounds__(256) void fused_kernel(
    const int* __restrict__ pe, const float* __restrict__ pdisp,
    const float* __restrict__ cell, const float* __restrict__ atom_xyz,
    const float* __restrict__ probe_xyz,
    const float* __restrict__ O,
    const float* __restrict__ W1, const float* __restrict__ b1,
    const float* __restrict__ W2, const float* __restrict__ b2,
    const float* __restrict__ W3, const float* __restrict__ b3,
    float* __restrict__ out) {
  __shared__ float sdx[CHUNK], sdy[CHUNK], sdz[CHUNK];
  __shared__ unsigned sap[CHUNK];
  __shared__ int mcnt;
  __shared__ float epS[NE][DRBF];
  __shared__ float h2S[NE][FH];
  __shared__ float part2[4][NE][64];
  __shared__ float rS[NE][3];
  __shared__ unsigned aS[NE];
  __shared__ float cwS[NE];
  __shared__ unsigned pS[NE];

  const int t    = threadIdx.x;
  const int lane = t & 63;
  const int wave = t >> 6;
  if (t == 0) mcnt = 0;
  __syncthreads();

  // ---- Phase F: filter this block's 256 edges (1/thread) ----
  const int e = blockIdx.x * CHUNK + t;
  const int b = blockIdx.x >> 7;          // 128 blocks per batch
  const float* cb = cell + b * 9;
  {
    int2 ap = ((const int2*)pe)[e];
    float pd0 = pdisp[e*3], pd1 = pdisp[e*3+1], pd2 = pdisp[e*3+2];
    float d0 = pd0*cb[0] + pd1*cb[3] + pd2*cb[6];
    float d1 = pd0*cb[1] + pd1*cb[4] + pd2*cb[7];
    float d2 = pd0*cb[2] + pd1*cb[5] + pd2*cb[8];
    int ag = b*NN + ap.x;
    int pg = b*PP + ap.y;
    float dx = probe_xyz[pg*3]   - (atom_xyz[ag*3]   + d0);
    float dy = probe_xyz[pg*3+1] - (atom_xyz[ag*3+1] + d1);
    float dz = probe_xyz[pg*3+2] - (atom_xyz[ag*3+2] + d2);
    float dist2 = dx*dx + dy*dy + dz*dz;
    if (dist2 < CUT*CUT) {
      int s = atomicAdd(&mcnt, 1);   // LDS atomic
      sdx[s] = dx; sdy[s] = dy; sdz[s] = dz;
      sap[s] = ((unsigned)ag << 16) | (unsigned)pg;
    }
  }
  __syncthreads();
  const int m = mcnt;
  if (m == 0) return;

  const int f1 = t & 127;     // L1 feature
  const int eh = t >> 7;      // L1 edge-half
  const float b1v = b1[f1];
  const float b2v = b2[lane];
  const float w3v = W3[lane];
  const float b3v = b3[0];

  for (int s0 = 0; s0 < m; s0 += NE) {
    {
      const int s = s0 + wave;
      float dx, dy, dz; unsigned ap_;
      if (s < m) { dx = sdx[s]; dy = sdy[s]; dz = sdz[s]; ap_ = sap[s]; }
      else       { dx = 1.f; dy = 0.f; dz = 0.f; ap_ = 0xFFFFFFFFu; }
      float d = sqrtf(dx*dx + dy*dy + dz*dz);
      float inv = 1.0f / (d + 1e-8f);
      if (lane < DRBF) epS[wave][lane] = sinf(d * (float)(lane+1) * (PI_F/CUT)) / d;
      if (lane == 0) {
        rS[wave][0] = dx*inv; rS[wave][1] = dy*inv; rS[wave][2] = dz*inv;
        aS[wave] = (ap_ == 0xFFFFFFFFu) ? 0u : (ap_ >> 16);
        cwS[wave] = 0.5f * (cosf((PI_F/CUT) * d) + 1.0f);
        pS[wave]  = (ap_ == 0xFFFFFFFFu) ? 0xFFFFFFFFu : (ap_ & 0xFFFFu);
      }
    }
    __syncthreads();

    // L1: thread (f1, eh) -> z for edges eh*2, eh*2+1; ep as float4 broadcasts
    {
      const int e0 = eh*2, e1 = eh*2 + 1;
      const float* Oa  = O + (size_t)aS[e0] * 640 + f1;
      const float* Obp = O + (size_t)aS[e1] * 640 + f1;
      float o00 = Oa[0],  o01 = Oa[128],  o02 = Oa[256],  o03 = Oa[384],  o04 = Oa[512];
      float o10 = Obp[0], o11 = Obp[128], o12 = Obp[256], o13 = Obp[384], o14 = Obp[512];
      float z0 = b1v + o03 + o04 + rS[e0][0]*o00 + rS[e0][1]*o01 + rS[e0][2]*o02;
      float z1 = b1v + o13 + o14 + rS[e1][0]*o10 + rS[e1][1]*o11 + rS[e1][2]*o12;
      const float* Wb = W1 + f1;          // RBF rows 0..31 (loop-invariant)
      #pragma unroll
      for (int k4 = 0; k4 < DRBF/4; ++k4) {
        float4 ea = *(const float4*)&epS[e0][k4*4];
        float4 eb = *(const float4*)&epS[e1][k4*4];
        float w0 = Wb[(k4*4+0) * FH];
        float w1 = Wb[(k4*4+1) * FH];
        float w2 = Wb[(k4*4+2) * FH];
        float w3 = Wb[(k4*4+3) * FH];
        z0 = fmaf(ea.x, w0, z0); z1 = fmaf(eb.x, w0, z1);
        z0 = fmaf(ea.y, w1, z0); z1 = fmaf(eb.y, w1, z1);
        z0 = fmaf(ea.z, w2, z0); z1 = fmaf(eb.z, w2, z1);
        z0 = fmaf(ea.w, w3, z0); z1 = fmaf(eb.w, w3, z1);
      }
      h2S[e0][f1] = z0 / (1.0f + __expf(-z0));
      h2S[e1][f1] = z1 / (1.0f + __expf(-z1));
    }
    __syncthreads();

    // L2 (k-split): wave = k-quarter, lane = out-feature
    {
      float a0 = 0.f, a1 = 0.f, a2 = 0.f, a3 = 0.f;
      const float* Wq = W2 + (wave * 32) * 64 + lane;
      const float* h0p = &h2S[0][wave * 32];
      const float* h1p = &h2S[1][wave * 32];
      const float* h2p = &h2S[2][wave * 32];
      const float* h3p = &h2S[3][wave * 32];
      #pragma unroll
      for (int k4 = 0; k4 < 8; ++k4) {
        float w0 = Wq[(k4*4 + 0) * 64];
        float w1 = Wq[(k4*4 + 1) * 64];
        float w2 = Wq[(k4*4 + 2) * 64];
        float w3 = Wq[(k4*4 + 3) * 64];
        float4 h0 = *(const float4*)&h0p[k4*4];
        float4 h1 = *(const float4*)&h1p[k4*4];
        float4 h2 = *(const float4*)&h2p[k4*4];
        float4 h3 = *(const float4*)&h3p[k4*4];
        a0 = fmaf(h0.x, w0, a0); a1 = fmaf(h1.x, w0, a1);
        a2 = fmaf(h2.x, w0, a2); a3 = fmaf(h3.x, w0, a3);
        a0 = fmaf(h0.y, w1, a0); a1 = fmaf(h1.y, w1, a1);
        a2 = fmaf(h2.y, w1, a2); a3 = fmaf(h3.y, w1, a3);
        a0 = fmaf(h0.z, w2, a0); a1 = fmaf(h1.z, w2, a1);
        a2 = fmaf(h2.z, w2, a2); a3 = fmaf(h3.z, w2, a3);
        a0 = fmaf(h0.w, w3, a0); a1 = fmaf(h1.w, w3, a1);
        a2 = fmaf(h2.w, w3, a2); a3 = fmaf(h3.w, w3, a3);
      }
      part2[wave][0][lane] = a0;
      part2[wave][1][lane] = a1;
      part2[wave][2][lane] = a2;
      part2[wave][3][lane] = a3;
    }
    __syncthreads();

    // finish: wave = edge, lane = out-feature; silu + W3-dot + scatter
    {
      float z = part2[0][wave][lane] + part2[1][wave][lane]
              + part2[2][wave][lane] + part2[3][wave][lane] + b2v;
      float h2 = z / (1.0f + __expf(-z));
      float rs = h2 * w3v;
      #pragma unroll
      for (int off = 32; off; off >>= 1) rs += __shfl_xor(rs, off, 64);
      if (lane == 0) {
        unsigned p = pS[wave];
        if (p != 0xFFFFFFFFu) atomicAdd(&out[p], (rs + b3v) * cwS[wave]);
      }
    }
    __syncthreads();
  }
}

extern "C" void kernel_launch(void* const* d_in, const int* in_sizes, int n_in,
                              void* d_out, int out_size, void* d_ws, size_t ws_size,
                              hipStream_t stream) {
  const float* S         = (const float*)d_in[0];
  const float* V         = (const float*)d_in[1];
  const float* atom_xyz  = (const float*)d_in[2];
  const float* probe_xyz = (const float*)d_in[3];
  const float* cell      = (const float*)d_in[4];
  const float* pdisp     = (const float*)d_in[5];
  const float* W1        = (const float*)d_in[6];
  const float* b1        = (const float*)d_in[7];
  const float* W2        = (const float*)d_in[8];
  const float* b2        = (const float*)d_in[9];
  const float* W3        = (const float*)d_in[10];
  const float* b3        = (const float*)d_in[11];
  const int*   pe        = (const int*)d_in[12];
  float* out = (float*)d_out;

  float* O = (float*)((char*)d_ws + 256);   // 2048 x 640 floats

  atom_kernel<<<(BB*NN/AT2)*5, 256, 0, stream>>>(S, V, W1, O, out);
  fused_kernel<<<BB*EE/CHUNK, 256, 0, stream>>>(pe, pdisp, cell, atom_xyz, probe_xyz,
                                                O, W1, b1, W2, b2, W3, b3, out);
}